// Round 8
// baseline (41637.994 us; speedup 1.0000x reference)
//
#include <hip/hip_runtime.h>
#include <stdint.h>
#include <stddef.h>

// ---------------------------------------------------------------------------
// Autoregressive decoder for MI355X (gfx950) — ONE kernel per step.
// v7 lessons: fp8 LDS-table decode regressed (+18us/step) -> bf16 restored;
// the done-counter/spin producer->consumer pattern passed -> generalized.
// k_step (grid 593, producers at lower blockIdx than consumers):
//   0..63    GRU0 (A = co bf16 plain [prev launch], B = WF) -> h0b via sc
//            stores, done_h0++
//   64..71   mel t-1 via MFMA (Wp bf16-swizzled), plain co [prev launch]
//   72       gate t-1 (dot, plain co)
//   73..80   zero ctx/den via sc stores, done_z++
//   81..144  GRU1: spin done_h0, h0b via sc gemv; h1f/h1b via sc stores,
//            done_h1++
//   145..208 gh0' = h0@W_hh0^T: spin done_h0, sc gemv; gh0 plain (next launch)
//   209..464 attn: spin done_h1&done_z; h1f via sc; bf16 energy/enc plain
//            (prologue data, L2-hot); ctx/den atomics; done_ctx++
//   465..528 gh1': spin done_h1; h1b sc gemv; gh1 plain (next launch)
//   529..592 co: spin done_ctx; [h1b | ctx*inv] all-sc gemv; cof/cob plain
// Counters monotonic in t (no resets); spins bounded (wrong-not-hung).
// Cross-launch traffic plain (boundary = acquire+flush); in-kernel cross-WG
// traffic via LLC (device atomics + SYSTEM-scope ld/st) — both HW-validated
// in rounds 3/5/7.
// ---------------------------------------------------------------------------

#define TM 400

typedef unsigned short ushort_t;
typedef unsigned long long u64_t;
typedef short    short8  __attribute__((ext_vector_type(8)));
typedef float    float4v __attribute__((ext_vector_type(4)));

#define DEVI static __device__ __forceinline__

// swizzled-weight segment bases (in shorts, within g_sw)
#define SB_WF   0
#define SB_IH1  3145728
#define SB_HH0  6291456
#define SB_HH1  9437184
#define SB_AT   12582912
#define SB_WC   13631488
#define SB_WP   15728640
#define SW_TOT  15859712

__device__ __align__(16) ushort_t g_sw[SW_TOT];      // bf16 weights (L2-hot)
__device__ __align__(16) float    g_wf[3145728];     // WF = W_ih0 @ Wp (fp32)
__device__ __align__(16) ushort_t g_encb[16777216];  // enc bf16 [32][512][1024]
__device__ __align__(16) ushort_t g_energy[16777216];// energy bf16 (incl b_attn)
__device__ __align__(16) ushort_t g_h0b[32768], g_h1b[32768];
__device__ __align__(16) float    g_h0f[32768], g_h1f[32768];
__device__ __align__(16) float    g_b0f[3072];
__device__ __align__(16) float    g_gh0[98304], g_gh1[98304];
__device__ __align__(16) float    g_ctxn[32768], g_sden[32];   // LLC atomics
__device__ __align__(16) float    g_cof[32768];      // co fp32
__device__ __align__(16) ushort_t g_cob[32768];      // co bf16
__device__ __align__(64) unsigned g_cnt[64];         // [0]=h0 [16]=h1 [32]=z [48]=ctx

DEVI ushort_t f2b(float f) {                // float -> bf16 bits, RNE
  union { float f; uint32_t u; } c; c.f = f;
  uint32_t u = c.u + 0x7fffu + ((c.u >> 16) & 1u);
  return (ushort_t)(u >> 16);
}
DEVI float b2f(ushort_t b) {
  union { uint32_t u; float f; } c; c.u = ((uint32_t)b) << 16; return c.f;
}
DEVI float sigm(float x) { return 1.f / (1.f + __expf(-x)); }

DEVI float4v mfma16(short8 a, short8 b, float4v c) {
  return __builtin_amdgcn_mfma_f32_16x16x32_bf16(a, b, c, 0, 0, 0);
}

// ---- LLC-coherent helpers (SYSTEM scope -> sc0 sc1, compiler-tracked) -----
DEVI u64_t ld_sc8(const void* p) {
  return __hip_atomic_load((const u64_t*)p, __ATOMIC_RELAXED,
                           __HIP_MEMORY_SCOPE_SYSTEM);
}
DEVI float ld_scf(const float* p) {
  return __hip_atomic_load(p, __ATOMIC_RELAXED, __HIP_MEMORY_SCOPE_SYSTEM);
}
DEVI void st_scf(float* p, float v) {
  __hip_atomic_store(p, v, __ATOMIC_RELAXED, __HIP_MEMORY_SCOPE_SYSTEM);
}
DEVI void st_scu(unsigned* p, unsigned v) {
  __hip_atomic_store(p, v, __ATOMIC_RELAXED, __HIP_MEMORY_SCOPE_SYSTEM);
}
DEVI void bump(unsigned* ctr) {
  __hip_atomic_fetch_add(ctr, 1u, __ATOMIC_RELAXED, __HIP_MEMORY_SCOPE_AGENT);
}
DEVI unsigned ldc(const unsigned* ctr) {
  return __hip_atomic_load(ctr, __ATOMIC_RELAXED, __HIP_MEMORY_SCOPE_AGENT);
}
DEVI void spin1(const unsigned* c, unsigned tgt) {
  unsigned sp = 0;
  while (ldc(c) < tgt) {
    __builtin_amdgcn_s_sleep(2);
    if (++sp > (1u << 22)) break;          // proceed (wrong, not hung)
  }
}

// A: bf16 [32 x 1024] row-major (plain loads); B: pre-swizzled frags. K=1024.
DEVI float4v gemm_plain(const ushort_t* Ab, const ushort_t* Bw,
                        int ntile, int mu, int lane) {
  float4v acc = {0.f, 0.f, 0.f, 0.f};
  const ushort_t* a = Ab + (size_t)(mu * 16 + (lane & 15)) * 1024 + ((lane >> 4) << 3);
  const ushort_t* b = Bw + ((size_t)ntile * 32 * 64 + lane) * 8;
  for (int kb = 0; kb < 32; ++kb) {
    short8 av = *(const short8*)(a + kb * 32);
    acc = mfma16(av, *(const short8*)(b + (size_t)kb * 512), acc);
  }
  return acc;
}

// Same, but A rows come through the LLC (sc loads), 32 in flight per chunk.
DEVI float4v gemm_sc(const ushort_t* Ab, const ushort_t* Bw,
                     int ntile, int mu, int lane) {
  float4v acc = {0.f, 0.f, 0.f, 0.f};
  const ushort_t* a = Ab + (size_t)(mu * 16 + (lane & 15)) * 1024 + ((lane >> 4) << 3);
  const ushort_t* b = Bw + ((size_t)ntile * 32 * 64 + lane) * 8;
  for (int c = 0; c < 2; ++c) {
    u64_t lo[16], hi[16];
#pragma unroll
    for (int j = 0; j < 16; ++j) {
      lo[j] = ld_sc8(a + (c * 16 + j) * 32);
      hi[j] = ld_sc8(a + (c * 16 + j) * 32 + 4);
    }
#pragma unroll
    for (int j = 0; j < 16; ++j) {
      union { u64_t u[2]; short8 s; } cv; cv.u[0] = lo[j]; cv.u[1] = hi[j];
      acc = mfma16(cv.s, *(const short8*)(b + (size_t)(c * 16 + j) * 512), acc);
    }
  }
  return acc;
}

// co gemv: K=2048, A = [h1b bf16 (sc) | ctx*inv f32->bf16 (sc)]
DEVI float4v gemm_co(const ushort_t* h1b, const float* ctxn, const float* sden,
                     const ushort_t* Bw, int ntile, int mu, int lane) {
  float4v acc = {0.f, 0.f, 0.f, 0.f};
  const int m = mu * 16 + (lane & 15), ko = (lane >> 4) << 3;
  const ushort_t* a0 = h1b + (size_t)m * 1024 + ko;
  const float* a1 = ctxn + (size_t)m * 1024 + ko;
  const float den = ld_scf(&sden[m]);
  const float inv = (den > 1e-35f) ? (1.f / den) : 0.f;
  const ushort_t* b = Bw + ((size_t)ntile * 64 * 64 + lane) * 8;
  for (int c = 0; c < 2; ++c) {
    u64_t lo[16], hi[16];
#pragma unroll
    for (int j = 0; j < 16; ++j) {
      lo[j] = ld_sc8(a0 + (c * 16 + j) * 32);
      hi[j] = ld_sc8(a0 + (c * 16 + j) * 32 + 4);
    }
#pragma unroll
    for (int j = 0; j < 16; ++j) {
      union { u64_t u[2]; short8 s; } cv; cv.u[0] = lo[j]; cv.u[1] = hi[j];
      acc = mfma16(cv.s, *(const short8*)(b + (size_t)(c * 16 + j) * 512), acc);
    }
  }
  for (int c = 0; c < 4; ++c) {
    u64_t t[32];
#pragma unroll
    for (int j = 0; j < 8; ++j)
#pragma unroll
      for (int q = 0; q < 4; ++q)
        t[j * 4 + q] = ld_sc8(a1 + (c * 8 + j) * 32 + q * 2);
#pragma unroll
    for (int j = 0; j < 8; ++j) {
      short8 av;
#pragma unroll
      for (int q = 0; q < 4; ++q) {
        union { u64_t u; float f[2]; } w; w.u = t[j * 4 + q];
        av[q * 2]     = (short)f2b(w.f[0] * inv);
        av[q * 2 + 1] = (short)f2b(w.f[1] * inv);
      }
      acc = mfma16(av, *(const short8*)(b + (size_t)(32 + c * 8 + j) * 512), acc);
    }
  }
  return acc;
}

// scatter C-fragment into LDS: sh[q*256 + m*16 + n]
DEVI void put_tile(float* sh, int q, int lane, float4v a) {
  const int base = q * 256 + (lane & 15);
#pragma unroll
  for (int i = 0; i < 4; ++i) sh[base + ((lane >> 4) * 4 + i) * 16] = a[i];
}

// ---------------------------------------------------------------------------
// Prologue: WF = W_ih0 @ Wp  (fp32, [3072 x 1024])
// ---------------------------------------------------------------------------
__global__ void k_wf(const float* __restrict__ Wih0, const float* __restrict__ Wp) {
  __shared__ __align__(16) float As[32][128];
  __shared__ __align__(16) float Bs[128][64];
  const int tid = threadIdx.x;
  const int nt = blockIdx.x >> 4, kt = blockIdx.x & 15;
  const int n0 = nt * 32, k0 = kt * 64;
  {
    const int r = tid >> 3, c0 = (tid & 7) * 16;
    for (int i = 0; i < 16; i += 4)
      *(float4v*)&As[r][c0 + i] = *(const float4v*)&Wih0[(size_t)(n0 + r) * 128 + c0 + i];
  }
  {
    const int r = tid >> 1, c0 = (tid & 1) * 32;
    for (int i = 0; i < 32; i += 4)
      *(float4v*)&Bs[r][c0 + i] = *(const float4v*)&Wp[(size_t)r * 1024 + k0 + c0 + i];
  }
  __syncthreads();
  const int rn = tid >> 3, kq = (tid & 7) * 8;
  float acc[8] = {0.f, 0.f, 0.f, 0.f, 0.f, 0.f, 0.f, 0.f};
  for (int m = 0; m < 128; ++m) {
    const float a = As[rn][m];
#pragma unroll
    for (int j = 0; j < 8; ++j) acc[j] += a * Bs[m][kq + j];
  }
  float* dst = g_wf + (size_t)(n0 + rn) * 1024 + k0 + kq;
#pragma unroll
  for (int j = 0; j < 8; ++j) dst[j] = acc[j];
}

// Prologue: enc fp32 -> bf16 (same [32][512][1024] layout).
__global__ void k_encb(const float* __restrict__ enc) {
  const size_t i = ((size_t)blockIdx.x * 256 + threadIdx.x) * 8;
  if (i >= 16777216) return;
  float4v a = *(const float4v*)(enc + i);
  float4v b = *(const float4v*)(enc + i + 4);
  short8 r;
#pragma unroll
  for (int j = 0; j < 4; ++j) { r[j] = (short)f2b(a[j]); r[4 + j] = (short)f2b(b[j]); }
  *(short8*)(g_encb + i) = r;
}

// ---------------------------------------------------------------------------
// Prologue: round fp32 weights to bf16 and repack into B-fragment order.
// lane L holds B[k = kb*32 + (L>>4)*8 + i][n = ntile*16 + (L&15)]
// ---------------------------------------------------------------------------
__global__ void k_swz(const float* __restrict__ W1, const float* __restrict__ W2,
                      const float* __restrict__ W3, const float* __restrict__ WA,
                      const float* __restrict__ WC, const float* __restrict__ Wp) {
  long fid = (long)blockIdx.x * 256 + threadIdx.x;
  if (fid >= 1982464) return;
  const float* src; int N, K; long base, local;
  if      (fid < 393216)  { src = g_wf; N = 3072; K = 1024; base = SB_WF;  local = fid; }
  else if (fid < 786432)  { src = W1;   N = 3072; K = 1024; base = SB_IH1; local = fid - 393216; }
  else if (fid < 1179648) { src = W2;   N = 3072; K = 1024; base = SB_HH0; local = fid - 786432; }
  else if (fid < 1572864) { src = W3;   N = 3072; K = 1024; base = SB_HH1; local = fid - 1179648; }
  else if (fid < 1703936) { src = WA;   N = 1024; K = 1024; base = SB_AT;  local = fid - 1572864; }
  else if (fid < 1966080) { src = WC;   N = 1024; K = 2048; base = SB_WC;  local = fid - 1703936; }
  else                    { src = Wp;   N = 128;  K = 1024; base = SB_WP;  local = fid - 1966080; }
  const int L = (int)(local & 63);
  long rest = local >> 6;
  const int KB = K >> 5;
  const int kb = (int)(rest % KB);
  const int nt = (int)(rest / KB);
  const int n  = nt * 16 + (L & 15);
  const int k0 = kb * 32 + ((L >> 4) << 3);
  short8 r;
#pragma unroll
  for (int i = 0; i < 8; ++i)
    r[i] = (short)f2b(src[(size_t)n * K + (k0 + i)]);
  *(short8*)(g_sw + base + local * 8) = r;
}

// ---------------------------------------------------------------------------
// Prologue: energy = enc @ W_attn^T + b_attn -> bf16 [32][512][1024].
// ---------------------------------------------------------------------------
__global__ void k_energy(const float* __restrict__ b_attn) {
  __shared__ __align__(16) float sh[2048];
  const int tid = threadIdx.x, lane = tid & 63, wv = tid >> 6;
  const int rt = blockIdx.x;
  const ushort_t* Ab = g_encb + (size_t)rt * 32 * 1024;
  float* shw = sh + wv * 512;
  for (int i = 0; i < 16; ++i) {
    const int nt = wv * 16 + i;
    put_tile(shw, 0, lane, gemm_plain(Ab, g_sw + SB_AT, nt, 0, lane));
    put_tile(shw, 1, lane, gemm_plain(Ab, g_sw + SB_AT, nt, 1, lane));
    __syncthreads();
    const int row = lane >> 1, cf = (lane & 1) * 8;
    const int q = row >> 4, r = row & 15;
    short8 o;
#pragma unroll
    for (int j = 0; j < 8; ++j) {
      const int n = nt * 16 + cf + j;
      o[j] = (short)f2b(shw[q * 256 + r * 16 + cf + j] + b_attn[n]);
    }
    *(short8*)(g_energy + (size_t)(rt * 32 + row) * 1024 + nt * 16 + cf) = o;
    __syncthreads();
  }
}

// Prologue: init states, mask output, fused bias b0f, counters.
__global__ void k_init(const float* __restrict__ ehid, const int* __restrict__ lens,
                       const float* __restrict__ Wih0, const float* __restrict__ bp,
                       const float* __restrict__ bih0,
                       float* __restrict__ out, int out_size) {
  int i = blockIdx.x * 256 + threadIdx.x;
  if (i < 64) g_cnt[i] = 0u;
  if (i < 32768) { float v = ehid[i]; g_h0f[i] = v; g_h0b[i] = f2b(v); }
  else if (i < 65536) {
    int j = i - 32768; float v = ehid[32768 + j];
    g_h1f[j] = v; g_h1b[j] = f2b(v);
  } else if (i < 78336) {
    int mi = i - 65536; int b = mi / 400, tt = mi % 400;
    int idx = 1651200 + mi;
    if (idx < out_size) out[idx] = (tt > lens[b]) ? 1.0f : 0.0f;
  } else if (i < 81408) {
    int n = i - 78336;
    float s = bih0[n];
    const float* wr = Wih0 + (size_t)n * 128;
    for (int m = 0; m < 128; ++m) s += bp[m] * wr[m];
    g_b0f[n] = s;
  }
}

// Prologue: gh0/gh1 for step 0 (h_init @ W_hh^T + b_hh).
__global__ void k_pre(const float* __restrict__ b_hh0, const float* __restrict__ b_hh1) {
  const int wg = blockIdx.x, tid = threadIdx.x;
  const int lane = tid & 63, wv = tid >> 6;
  __shared__ __align__(16) float sh[1536];
  const int qa = (wv < 2) ? wv * 2 : wv + 2;
  const int qb = (wv < 2) ? wv * 2 + 1 : -1;
  const ushort_t* Ab = (wg < 64) ? g_h0b : g_h1b;
  const ushort_t* Bw = g_sw + ((wg < 64) ? SB_HH0 : SB_HH1);
  const float* bhh = (wg < 64) ? b_hh0 : b_hh1;
  float* ghb = (wg < 64) ? g_gh0 : g_gh1;
  const int w16 = wg & 63;
  { int g = qa >> 1, mu = qa & 1;
    put_tile(sh, qa, lane, gemm_plain(Ab, Bw, g * 64 + w16, mu, lane)); }
  if (qb >= 0) { int g = qb >> 1, mu = qb & 1;
    put_tile(sh, qb, lane, gemm_plain(Ab, Bw, g * 64 + w16, mu, lane)); }
  __syncthreads();
  const int jl = tid & 15, mr = tid >> 4, jg = w16 * 16 + jl;
#pragma unroll
  for (int mu = 0; mu < 2; ++mu) {
    const int b = mu * 16 + mr;
#pragma unroll
    for (int g = 0; g < 3; ++g)
      ghb[b * 3072 + g * 1024 + jg] = sh[(g * 2 + mu) * 256 + tid] + bhh[g * 1024 + jg];
  }
}

// ---------------------------------------------------------------------------
// THE step kernel. Grid 593; roles by blockIdx (producers < consumers).
// ---------------------------------------------------------------------------
__global__ void __launch_bounds__(256) k_step(
    int t,
    const float* __restrict__ b_ih0, const float* __restrict__ b_ih1,
    const float* __restrict__ b_hh0, const float* __restrict__ b_hh1,
    const float* __restrict__ bc, const float* __restrict__ bp,
    const float* __restrict__ Wg, const float* __restrict__ bg,
    const int* __restrict__ lens, float* __restrict__ out, int out_size) {
  __shared__ __align__(16) float sh[4160];
  const int wg = blockIdx.x, tid = threadIdx.x;
  const int lane = tid & 63, wv = tid >> 6;
  if (wg < 64) {
    // ---- GRU0: A = co bf16 (prev launch, plain); publish h0b via sc ----
    const int qa = (wv < 2) ? wv * 2 : wv + 2;
    const int qb = (wv < 2) ? wv * 2 + 1 : -1;
    const ushort_t* SW = g_sw + SB_WF;
    float4v acc;
    { int g = qa >> 1, mu = qa & 1;
      acc = (t > 0) ? gemm_plain(g_cob, SW, g * 64 + wg, mu, lane)
                    : float4v{0.f, 0.f, 0.f, 0.f};
      put_tile(sh, qa, lane, acc); }
    if (qb >= 0) { int g = qb >> 1, mu = qb & 1;
      acc = (t > 0) ? gemm_plain(g_cob, SW, g * 64 + wg, mu, lane)
                    : float4v{0.f, 0.f, 0.f, 0.f};
      put_tile(sh, qb, lane, acc); }
    __syncthreads();
    const int jl = tid & 15, mr = tid >> 4, jg = wg * 16 + jl;
    const float* bs = (t > 0) ? g_b0f : b_ih0;
    const float bir = bs[jg], biz = bs[1024 + jg], bin = bs[2048 + jg];
#pragma unroll
    for (int mu = 0; mu < 2; ++mu) {
      const int b = mu * 16 + mr;
      float gr = sh[mu * 256 + tid]       + bir + g_gh0[b * 3072 + jg];
      float gz = sh[(2 + mu) * 256 + tid] + biz + g_gh0[b * 3072 + 1024 + jg];
      float gn = sh[(4 + mu) * 256 + tid] + bin;
      float r = sigm(gr), z = sigm(gz);
      float nn = tanhf(gn + r * g_gh0[b * 3072 + 2048 + jg]);
      float h = (1.f - z) * nn + z * g_h0f[b * 1024 + jg];
      g_h0f[b * 1024 + jg] = h;                    // own columns, plain
      ushort_t hb = f2b(h);
      ushort_t hb1 = (ushort_t)__shfl_down((int)hb, 1, 64);
      if (!(jl & 1))
        st_scu((unsigned*)&g_h0b[b * 1024 + jg],
               (unsigned)hb | ((unsigned)hb1 << 16));
    }
    __syncthreads();                               // drain sc stores
    if (tid == 0) bump(&g_cnt[0]);                 // h0 ready
  } else if (wg < 72) {
    // ---- mel t-1 via MFMA (plain co from prev launch) ----
    if (t == 0) return;
    const int nt = wg - 64;
    if (wv < 2)
      put_tile(sh, wv, lane, gemm_plain(g_cob, g_sw + SB_WP, nt, wv, lane));
    __syncthreads();
    const int jl = tid & 15, mr = tid >> 4;
    const int m = nt * 16 + jl;
    const float bpv = bp[m];
#pragma unroll
    for (int mu = 0; mu < 2; ++mu) {
      const int b = mu * 16 + mr;
      const bool mk = (t - 1) > lens[b];
      const float v = mk ? 0.f : (sh[mu * 256 + tid] + bpv);
      const int oidx = b * 51200 + (t - 1) * 128 + m;
      if (oidx < out_size) out[oidx] = v;
    }
  } else if (wg == 72) {
    // ---- gate t-1 (plain co) ----
    if (t == 0) return;
    const int b = tid >> 3, seg = tid & 7;
    const float* cop = g_cof + b * 1024 + seg * 128;
    const float* wgp = Wg + seg * 128;
    float s = 0.f;
#pragma unroll 8
    for (int k = 0; k < 128; k += 4) {
      float4v cv = *(const float4v*)(cop + k);
      float4v wv4 = *(const float4v*)(wgp + k);
      s += cv[0] * wv4[0] + cv[1] * wv4[1] + cv[2] * wv4[2] + cv[3] * wv4[3];
    }
    for (int o = 1; o < 8; o <<= 1) s += __shfl_xor(s, o, 64);
    if (seg == 0) {
      const bool mk = (t - 1) > lens[b];
      const float g = mk ? 1000.f : (s + bg[0]);
      const int oidx = 1638400 + b * 400 + (t - 1);
      if (oidx < out_size) out[oidx] = g;
    }
  } else if (wg < 81) {
    // ---- zero ctx/den via sc stores (prev co consumed them last launch) --
    const int z0 = (wg - 73) * 256 + tid;
#pragma unroll
    for (int r4 = 0; r4 < 16; ++r4) st_scf(&g_ctxn[z0 + r4 * 2048], 0.f);
    if (wg == 73 && tid < 32) st_scf(&g_sden[tid], 0.f);
    __syncthreads();
    if (tid == 0) bump(&g_cnt[32]);                // zero done
  } else if (wg < 145) {
    // ---- GRU1: spin h0; h0b via sc gemv; publish h1f/h1b via sc ----
    const int w16 = wg - 81;
    if (tid == 0) spin1(&g_cnt[0], (unsigned)(t + 1) * 64u);
    __syncthreads();
    const int qa = (wv < 2) ? wv * 2 : wv + 2;
    const int qb = (wv < 2) ? wv * 2 + 1 : -1;
    const ushort_t* SW = g_sw + SB_IH1;
    { int g = qa >> 1, mu = qa & 1;
      put_tile(sh, qa, lane, gemm_sc(g_h0b, SW, g * 64 + w16, mu, lane)); }
    if (qb >= 0) { int g = qb >> 1, mu = qb & 1;
      put_tile(sh, qb, lane, gemm_sc(g_h0b, SW, g * 64 + w16, mu, lane)); }
    __syncthreads();
    const int jl = tid & 15, mr = tid >> 4, jg = w16 * 16 + jl;
    const float bir = b_ih1[jg], biz = b_ih1[1024 + jg], bin = b_ih1[2048 + jg];
#pragma unroll
    for (int mu = 0; mu < 2; ++mu) {
      const int b = mu * 16 + mr;
      float gr = sh[mu * 256 + tid]       + bir + g_gh1[b * 3072 + jg];
      float gz = sh[(2 + mu) * 256 + tid] + biz + g_gh1[b * 3072 + 1024 + jg];
      float gn = sh[(4 + mu) * 256 + tid] + bin;
      float r = sigm(gr), z = sigm(gz);
      float nn = tanhf(gn + r * g_gh1[b * 3072 + 2048 + jg]);
      float h = (1.f - z) * nn + z * g_h1f[b * 1024 + jg];   // prev launch val
      st_scf(&g_h1f[b * 1024 + jg], h);
      ushort_t hb = f2b(h);
      ushort_t hb1 = (ushort_t)__shfl_down((int)hb, 1, 64);
      if (!(jl & 1))
        st_scu((unsigned*)&g_h1b[b * 1024 + jg],
               (unsigned)hb | ((unsigned)hb1 << 16));
    }
    __syncthreads();
    if (tid == 0) bump(&g_cnt[16]);                // h1 ready
  } else if (wg < 209) {
    // ---- gh0' for next step: spin h0; sc gemv; plain stores ----
    const int w16 = wg - 145;
    if (tid == 0) spin1(&g_cnt[0], (unsigned)(t + 1) * 64u);
    __syncthreads();
    const int qa = (wv < 2) ? wv * 2 : wv + 2;
    const int qb = (wv < 2) ? wv * 2 + 1 : -1;
    const ushort_t* SW = g_sw + SB_HH0;
    { int g = qa >> 1, mu = qa & 1;
      put_tile(sh, qa, lane, gemm_sc(g_h0b, SW, g * 64 + w16, mu, lane)); }
    if (qb >= 0) { int g = qb >> 1, mu = qb & 1;
      put_tile(sh, qb, lane, gemm_sc(g_h0b, SW, g * 64 + w16, mu, lane)); }
    __syncthreads();
    const int jl = tid & 15, mr = tid >> 4, jg = w16 * 16 + jl;
#pragma unroll
    for (int mu = 0; mu < 2; ++mu) {
      const int b = mu * 16 + mr;
#pragma unroll
      for (int g = 0; g < 3; ++g)
        g_gh0[b * 3072 + g * 1024 + jg] = sh[(g * 2 + mu) * 256 + tid] + b_hh0[g * 1024 + jg];
    }
  } else if (wg < 465) {
    // ---- attention: spin h1 & zero; bf16 energy/enc plain; atomics ----
    const int a = wg - 209, b = a >> 3, slot = a & 7;
    if (tid == 0) {
      spin1(&g_cnt[16], (unsigned)(t + 1) * 64u);
      spin1(&g_cnt[32], (unsigned)(t + 1) * 8u);
    }
    __syncthreads();
    const float* hp = g_h1f + b * 1024;
    float u0[8], u1[8];
    {
      union { u64_t u; float f[2]; } tt;
#pragma unroll
      for (int j = 0; j < 4; ++j) {
        tt.u = ld_sc8(hp + lane * 8 + j * 2);
        u0[j * 2] = tt.f[0]; u0[j * 2 + 1] = tt.f[1];
      }
#pragma unroll
      for (int j = 0; j < 4; ++j) {
        tt.u = ld_sc8(hp + 512 + lane * 8 + j * 2);
        u1[j * 2] = tt.f[0]; u1[j * 2 + 1] = tt.f[1];
      }
    }
    float cx0[8] = {0.f, 0.f, 0.f, 0.f, 0.f, 0.f, 0.f, 0.f};
    float cx1[8] = {0.f, 0.f, 0.f, 0.f, 0.f, 0.f, 0.f, 0.f};
    float sw = 0.f;
    const size_t base = ((size_t)(b * 512 + slot * 64 + wv * 16)) * 1024 + lane * 8;
    for (int it = 0; it < 16; ++it) {
      const size_t off = base + (size_t)it * 1024;
      short8 g0 = *(const short8*)(g_energy + off);
      short8 g1 = *(const short8*)(g_energy + off + 512);
      short8 e0 = *(const short8*)(g_encb + off);
      short8 e1 = *(const short8*)(g_encb + off + 512);
      float ef0[8], ef1[8];
      float s = 0.f;
#pragma unroll
      for (int j = 0; j < 8; ++j) {
        ef0[j] = b2f((ushort_t)e0[j]);
        ef1[j] = b2f((ushort_t)e1[j]);
        s += u0[j] * b2f((ushort_t)g0[j]) + u1[j] * b2f((ushort_t)g1[j]);
      }
      for (int o = 1; o < 64; o <<= 1) s += __shfl_xor(s, o, 64);
      const float sc = fminf(fmaxf(s, -70.f), 70.f);  // identity in legit regime
      const float p = __expf(sc);
      sw += p;
#pragma unroll
      for (int j = 0; j < 8; ++j) { cx0[j] += p * ef0[j]; cx1[j] += p * ef1[j]; }
    }
#pragma unroll
    for (int j = 0; j < 8; ++j) {
      sh[wv * 1024 + lane * 8 + j]       = cx0[j];
      sh[wv * 1024 + 512 + lane * 8 + j] = cx1[j];
    }
    if (lane == 0) sh[4096 + wv] = sw;
    __syncthreads();
    float4v t4 = {0.f, 0.f, 0.f, 0.f};
#pragma unroll
    for (int v = 0; v < 4; ++v) t4 += *(const float4v*)&sh[v * 1024 + tid * 4];
    float* dst = g_ctxn + b * 1024 + tid * 4;
#pragma unroll
    for (int c = 0; c < 4; ++c) unsafeAtomicAdd(dst + c, t4[c]);
    if (tid == 0)
      unsafeAtomicAdd(&g_sden[b], sh[4096] + sh[4097] + sh[4098] + sh[4099]);
    __syncthreads();                               // drain atomics
    if (tid == 0) bump(&g_cnt[48]);                // ctx contribution done
  } else if (wg < 529) {
    // ---- gh1' for next step: spin h1; h1b sc gemv; plain stores ----
    const int w16 = wg - 465;
    if (tid == 0) spin1(&g_cnt[16], (unsigned)(t + 1) * 64u);
    __syncthreads();
    const int qa = (wv < 2) ? wv * 2 : wv + 2;
    const int qb = (wv < 2) ? wv * 2 + 1 : -1;
    const ushort_t* SW = g_sw + SB_HH1;
    { int g = qa >> 1, mu = qa & 1;
      put_tile(sh, qa, lane, gemm_sc(g_h1b, SW, g * 64 + w16, mu, lane)); }
    if (qb >= 0) { int g = qb >> 1, mu = qb & 1;
      put_tile(sh, qb, lane, gemm_sc(g_h1b, SW, g * 64 + w16, mu, lane)); }
    __syncthreads();
    const int jl = tid & 15, mr = tid >> 4, jg = w16 * 16 + jl;
#pragma unroll
    for (int mu = 0; mu < 2; ++mu) {
      const int b = mu * 16 + mr;
#pragma unroll
      for (int g = 0; g < 3; ++g)
        g_gh1[b * 3072 + g * 1024 + jg] = sh[(g * 2 + mu) * 256 + tid] + b_hh1[g * 1024 + jg];
    }
  } else {
    // ---- co: spin ctx complete; all-sc gemv; plain stores (next launch) --
    const int w16 = wg - 529;
    if (tid == 0) spin1(&g_cnt[48], (unsigned)(t + 1) * 256u);
    __syncthreads();
    if (wv < 2)
      put_tile(sh, wv, lane, gemm_co(g_h1b, g_ctxn, g_sden, g_sw + SB_WC, w16, wv, lane));
    __syncthreads();
    const int jl = tid & 15, mr = tid >> 4;
    const float bcv = bc[w16 * 16 + jl];
#pragma unroll
    for (int mu = 0; mu < 2; ++mu) {
      const int b = mu * 16 + mr;
      const float v = tanhf(sh[mu * 256 + tid] + bcv);
      g_cof[b * 1024 + w16 * 16 + jl] = v;
      g_cob[b * 1024 + w16 * 16 + jl] = f2b(v);
    }
  }
}

// Final outputs for t = TM-1 (mel via MFMA + gate), after last k_step.
__global__ void k_fin(const float* __restrict__ bp, const float* __restrict__ Wg,
                      const float* __restrict__ bg, const int* __restrict__ lens,
                      float* __restrict__ out, int out_size) {
  __shared__ __align__(16) float sh[512];
  const int wg = blockIdx.x, tid = threadIdx.x;
  const int lane = tid & 63, wv = tid >> 6;
  if (wg < 8) {
    if (wv < 2)
      put_tile(sh, wv, lane, gemm_plain(g_cob, g_sw + SB_WP, wg, wv, lane));
    __syncthreads();
    const int jl = tid & 15, mr = tid >> 4;
    const int m = wg * 16 + jl;
    const float bpv = bp[m];
#pragma unroll
    for (int mu = 0; mu < 2; ++mu) {
      const int b = mu * 16 + mr;
      const bool mk = (TM - 1) > lens[b];
      const float v = mk ? 0.f : (sh[mu * 256 + tid] + bpv);
      const int oidx = b * 51200 + (TM - 1) * 128 + m;
      if (oidx < out_size) out[oidx] = v;
    }
  } else {
    const int b = tid >> 3, seg = tid & 7;
    const float* cop = g_cof + b * 1024 + seg * 128;
    const float* wgp = Wg + seg * 128;
    float s = 0.f;
#pragma unroll 8
    for (int k = 0; k < 128; k += 4) {
      float4v cv = *(const float4v*)(cop + k);
      float4v wv4 = *(const float4v*)(wgp + k);
      s += cv[0] * wv4[0] + cv[1] * wv4[1] + cv[2] * wv4[2] + cv[3] * wv4[3];
    }
    for (int o = 1; o < 8; o <<= 1) s += __shfl_xor(s, o, 64);
    if (seg == 0) {
      const bool mk = (TM - 1) > lens[b];
      const float g = mk ? 1000.f : (s + bg[0]);
      const int oidx = 1638400 + b * 400 + (TM - 1);
      if (oidx < out_size) out[oidx] = g;
    }
  }
}

extern "C" void kernel_launch(void* const* d_in, const int* in_sizes, int n_in,
                              void* d_out, int out_size, void* d_ws, size_t ws_size,
                              hipStream_t stream) {
  const float* ehid  = (const float*)d_in[0];
  const float* enc   = (const float*)d_in[1];
  const int*   lens  = (const int*)d_in[3];
  const float* W_attn= (const float*)d_in[4];
  const float* b_attn= (const float*)d_in[5];
  const float* W_ih0 = (const float*)d_in[6];
  const float* W_hh0 = (const float*)d_in[7];
  const float* b_ih0 = (const float*)d_in[8];
  const float* b_hh0 = (const float*)d_in[9];
  const float* W_ih1 = (const float*)d_in[10];
  const float* W_hh1 = (const float*)d_in[11];
  const float* b_ih1 = (const float*)d_in[12];
  const float* b_hh1 = (const float*)d_in[13];
  const float* Wc    = (const float*)d_in[14];
  const float* bc    = (const float*)d_in[15];
  const float* Wp    = (const float*)d_in[16];
  const float* bp    = (const float*)d_in[17];
  const float* Wg    = (const float*)d_in[18];
  const float* bg    = (const float*)d_in[19];
  float* out = (float*)d_out;

  k_wf    <<<1536, 256, 0, stream>>>(W_ih0, Wp);
  k_encb  <<<8192, 256, 0, stream>>>(enc);
  k_swz   <<<7744, 256, 0, stream>>>(W_ih1, W_hh0, W_hh1, W_attn, Wc, Wp);
  k_energy<<<512,  256, 0, stream>>>(b_attn);
  k_init  <<<318,  256, 0, stream>>>(ehid, lens, W_ih0, bp, b_ih0, out, out_size);
  k_pre   <<<128,  256, 0, stream>>>(b_hh0, b_hh1);
  for (int t = 0; t < TM; ++t)
    k_step<<<593, 256, 0, stream>>>(t, b_ih0, b_ih1, b_hh0, b_hh1, bc, bp,
                                    Wg, bg, lens, out, out_size);
  k_fin<<<9, 256, 0, stream>>>(bp, Wg, bg, lens, out, out_size);
}

// Round 10
// 23727.374 us; speedup vs baseline: 1.7549x; 1.7549x over previous
//
#include <hip/hip_runtime.h>
#include <stdint.h>
#include <stddef.h>

// ---------------------------------------------------------------------------
// Autoregressive decoder for MI355X (gfx950) — multi-launch, 3 kernels/step.
// v10 = composition of ONLY HW-validated pieces:
//   - v7's 3-launch structure (passed): s1 (GRU0 + mel-MFMA + gate + zero),
//     s2 (GRU1 + gh0'), s34 (attn -> single handoff -> co, + gh1' riders).
//   - v6's bf16 attention inner loop (passed; v7's fp8 LDS-table decode was
//     the regression: serialized bank-conflicted ds_reads, +18us/step).
//   - v8's monotonic counters (passed; no per-step resets).
//   - Spin bound 2^18 (~80ms worst-case) so a broken handoff = fast wrong
//     answer, never a watchdog kill.
// Per step: s1 -> s2 -> s34. Kernel boundaries publish all plain traffic;
// in-kernel cross-WG traffic via LLC only (device atomics + SYSTEM-scope
// loads) — the coherence rules every passing round has obeyed.
// ---------------------------------------------------------------------------

#define TM 400

typedef unsigned short ushort_t;
typedef unsigned long long u64_t;
typedef short    short8  __attribute__((ext_vector_type(8)));
typedef float    float4v __attribute__((ext_vector_type(4)));

#define DEVI static __device__ __forceinline__

// swizzled-weight segment bases (in shorts, within g_sw)
#define SB_WF   0
#define SB_IH1  3145728
#define SB_HH0  6291456
#define SB_HH1  9437184
#define SB_AT   12582912
#define SB_WC   13631488
#define SB_WP   15728640
#define SW_TOT  15859712

__device__ __align__(16) ushort_t g_sw[SW_TOT];      // bf16 weights (L2-hot)
__device__ __align__(16) float    g_wf[3145728];     // WF = W_ih0 @ Wp (fp32)
__device__ __align__(16) ushort_t g_encb[16777216];  // enc bf16 [32][512][1024]
__device__ __align__(16) ushort_t g_energy[16777216];// energy bf16 (incl b_attn)
__device__ __align__(16) ushort_t g_h0b[32768], g_h1b[32768];
__device__ __align__(16) float    g_h0f[32768], g_h1f[32768];
__device__ __align__(16) float    g_b0f[3072];
__device__ __align__(16) float    g_gh0[98304], g_gh1[98304];
__device__ __align__(16) float    g_ctxn[32768], g_sden[32];   // LLC atomics
__device__ __align__(16) float    g_cof[32768];      // co fp32
__device__ __align__(16) ushort_t g_cob[32768];      // co bf16
__device__ __align__(64) unsigned g_cnt[16];         // [0] = ctx done (monotonic)

DEVI ushort_t f2b(float f) {                // float -> bf16 bits, RNE
  union { float f; uint32_t u; } c; c.f = f;
  uint32_t u = c.u + 0x7fffu + ((c.u >> 16) & 1u);
  return (ushort_t)(u >> 16);
}
DEVI float b2f(ushort_t b) {
  union { uint32_t u; float f; } c; c.u = ((uint32_t)b) << 16; return c.f;
}
DEVI float sigm(float x) { return 1.f / (1.f + __expf(-x)); }

DEVI float4v mfma16(short8 a, short8 b, float4v c) {
  return __builtin_amdgcn_mfma_f32_16x16x32_bf16(a, b, c, 0, 0, 0);
}

// ---- LLC-coherent helpers (SYSTEM scope -> sc0 sc1, compiler-tracked) -----
DEVI u64_t ld_sc8(const void* p) {
  return __hip_atomic_load((const u64_t*)p, __ATOMIC_RELAXED,
                           __HIP_MEMORY_SCOPE_SYSTEM);
}
DEVI float ld_scf(const float* p) {
  return __hip_atomic_load(p, __ATOMIC_RELAXED, __HIP_MEMORY_SCOPE_SYSTEM);
}
DEVI void bump(unsigned* ctr) {
  __hip_atomic_fetch_add(ctr, 1u, __ATOMIC_RELAXED, __HIP_MEMORY_SCOPE_AGENT);
}
DEVI unsigned ldc(const unsigned* ctr) {
  return __hip_atomic_load(ctr, __ATOMIC_RELAXED, __HIP_MEMORY_SCOPE_AGENT);
}
DEVI void spin1(const unsigned* c, unsigned tgt) {
  unsigned sp = 0;
  while (ldc(c) < tgt) {
    __builtin_amdgcn_s_sleep(2);
    if (++sp > (1u << 18)) break;          // ~80ms cap: wrong, never hung
  }
}

// A: bf16 [32 x 1024] row-major (plain loads); B: pre-swizzled frags. K=1024.
DEVI float4v gemm_plain(const ushort_t* Ab, const ushort_t* Bw,
                        int ntile, int mu, int lane) {
  float4v acc = {0.f, 0.f, 0.f, 0.f};
  const ushort_t* a = Ab + (size_t)(mu * 16 + (lane & 15)) * 1024 + ((lane >> 4) << 3);
  const ushort_t* b = Bw + ((size_t)ntile * 32 * 64 + lane) * 8;
  for (int kb = 0; kb < 32; ++kb) {
    short8 av = *(const short8*)(a + kb * 32);
    acc = mfma16(av, *(const short8*)(b + (size_t)kb * 512), acc);
  }
  return acc;
}

// co gemv: K=2048, A = [h1b bf16 PLAIN (s2 boundary) | ctx*inv via sc loads]
DEVI float4v gemm_co(const ushort_t* h1b, const float* ctxn, const float* sden,
                     const ushort_t* Bw, int ntile, int mu, int lane) {
  float4v acc = {0.f, 0.f, 0.f, 0.f};
  const int m = mu * 16 + (lane & 15), ko = (lane >> 4) << 3;
  const ushort_t* a0 = h1b + (size_t)m * 1024 + ko;
  const float* a1 = ctxn + (size_t)m * 1024 + ko;
  const float den = ld_scf(&sden[m]);
  const float inv = (den > 1e-35f) ? (1.f / den) : 0.f;
  const ushort_t* b = Bw + ((size_t)ntile * 64 * 64 + lane) * 8;
  for (int kb = 0; kb < 32; ++kb)
    acc = mfma16(*(const short8*)(a0 + kb * 32),
                 *(const short8*)(b + (size_t)kb * 512), acc);
  for (int c = 0; c < 4; ++c) {          // 8 kbs/chunk, 32 sc loads in flight
    u64_t t[32];
#pragma unroll
    for (int j = 0; j < 8; ++j)
#pragma unroll
      for (int q = 0; q < 4; ++q)
        t[j * 4 + q] = ld_sc8(a1 + (c * 8 + j) * 32 + q * 2);
#pragma unroll
    for (int j = 0; j < 8; ++j) {
      short8 av;
#pragma unroll
      for (int q = 0; q < 4; ++q) {
        union { u64_t u; float f[2]; } w; w.u = t[j * 4 + q];
        av[q * 2]     = (short)f2b(w.f[0] * inv);
        av[q * 2 + 1] = (short)f2b(w.f[1] * inv);
      }
      acc = mfma16(av, *(const short8*)(b + (size_t)(32 + c * 8 + j) * 512), acc);
    }
  }
  return acc;
}

// scatter C-fragment into LDS: sh[q*256 + m*16 + n]
DEVI void put_tile(float* sh, int q, int lane, float4v a) {
  const int base = q * 256 + (lane & 15);
#pragma unroll
  for (int i = 0; i < 4; ++i) sh[base + ((lane >> 4) * 4 + i) * 16] = a[i];
}

// ---------------------------------------------------------------------------
// Prologue: WF = W_ih0 @ Wp  (fp32, [3072 x 1024])
// ---------------------------------------------------------------------------
__global__ void k_wf(const float* __restrict__ Wih0, const float* __restrict__ Wp) {
  __shared__ __align__(16) float As[32][128];
  __shared__ __align__(16) float Bs[128][64];
  const int tid = threadIdx.x;
  const int nt = blockIdx.x >> 4, kt = blockIdx.x & 15;
  const int n0 = nt * 32, k0 = kt * 64;
  {
    const int r = tid >> 3, c0 = (tid & 7) * 16;
    for (int i = 0; i < 16; i += 4)
      *(float4v*)&As[r][c0 + i] = *(const float4v*)&Wih0[(size_t)(n0 + r) * 128 + c0 + i];
  }
  {
    const int r = tid >> 1, c0 = (tid & 1) * 32;
    for (int i = 0; i < 32; i += 4)
      *(float4v*)&Bs[r][c0 + i] = *(const float4v*)&Wp[(size_t)r * 1024 + k0 + c0 + i];
  }
  __syncthreads();
  const int rn = tid >> 3, kq = (tid & 7) * 8;
  float acc[8] = {0.f, 0.f, 0.f, 0.f, 0.f, 0.f, 0.f, 0.f};
  for (int m = 0; m < 128; ++m) {
    const float a = As[rn][m];
#pragma unroll
    for (int j = 0; j < 8; ++j) acc[j] += a * Bs[m][kq + j];
  }
  float* dst = g_wf + (size_t)(n0 + rn) * 1024 + k0 + kq;
#pragma unroll
  for (int j = 0; j < 8; ++j) dst[j] = acc[j];
}

// Prologue: enc fp32 -> bf16 (same [32][512][1024] layout).
__global__ void k_encb(const float* __restrict__ enc) {
  const size_t i = ((size_t)blockIdx.x * 256 + threadIdx.x) * 8;
  if (i >= 16777216) return;
  float4v a = *(const float4v*)(enc + i);
  float4v b = *(const float4v*)(enc + i + 4);
  short8 r;
#pragma unroll
  for (int j = 0; j < 4; ++j) { r[j] = (short)f2b(a[j]); r[4 + j] = (short)f2b(b[j]); }
  *(short8*)(g_encb + i) = r;
}

// ---------------------------------------------------------------------------
// Prologue: round fp32 weights to bf16 and repack into B-fragment order.
// lane L holds B[k = kb*32 + (L>>4)*8 + i][n = ntile*16 + (L&15)]
// ---------------------------------------------------------------------------
__global__ void k_swz(const float* __restrict__ W1, const float* __restrict__ W2,
                      const float* __restrict__ W3, const float* __restrict__ WA,
                      const float* __restrict__ WC, const float* __restrict__ Wp) {
  long fid = (long)blockIdx.x * 256 + threadIdx.x;
  if (fid >= 1982464) return;
  const float* src; int N, K; long base, local;
  if      (fid < 393216)  { src = g_wf; N = 3072; K = 1024; base = SB_WF;  local = fid; }
  else if (fid < 786432)  { src = W1;   N = 3072; K = 1024; base = SB_IH1; local = fid - 393216; }
  else if (fid < 1179648) { src = W2;   N = 3072; K = 1024; base = SB_HH0; local = fid - 786432; }
  else if (fid < 1572864) { src = W3;   N = 3072; K = 1024; base = SB_HH1; local = fid - 1179648; }
  else if (fid < 1703936) { src = WA;   N = 1024; K = 1024; base = SB_AT;  local = fid - 1572864; }
  else if (fid < 1966080) { src = WC;   N = 1024; K = 2048; base = SB_WC;  local = fid - 1703936; }
  else                    { src = Wp;   N = 128;  K = 1024; base = SB_WP;  local = fid - 1966080; }
  const int L = (int)(local & 63);
  long rest = local >> 6;
  const int KB = K >> 5;
  const int kb = (int)(rest % KB);
  const int nt = (int)(rest / KB);
  const int n  = nt * 16 + (L & 15);
  const int k0 = kb * 32 + ((L >> 4) << 3);
  short8 r;
#pragma unroll
  for (int i = 0; i < 8; ++i)
    r[i] = (short)f2b(src[(size_t)n * K + (k0 + i)]);
  *(short8*)(g_sw + base + local * 8) = r;
}

// ---------------------------------------------------------------------------
// Prologue: energy = enc @ W_attn^T + b_attn -> bf16 [32][512][1024].
// ---------------------------------------------------------------------------
__global__ void k_energy(const float* __restrict__ b_attn) {
  __shared__ __align__(16) float sh[2048];
  const int tid = threadIdx.x, lane = tid & 63, wv = tid >> 6;
  const int rt = blockIdx.x;
  const ushort_t* Ab = g_encb + (size_t)rt * 32 * 1024;
  float* shw = sh + wv * 512;
  for (int i = 0; i < 16; ++i) {
    const int nt = wv * 16 + i;
    put_tile(shw, 0, lane, gemm_plain(Ab, g_sw + SB_AT, nt, 0, lane));
    put_tile(shw, 1, lane, gemm_plain(Ab, g_sw + SB_AT, nt, 1, lane));
    __syncthreads();
    const int row = lane >> 1, cf = (lane & 1) * 8;
    const int q = row >> 4, r = row & 15;
    short8 o;
#pragma unroll
    for (int j = 0; j < 8; ++j) {
      const int n = nt * 16 + cf + j;
      o[j] = (short)f2b(shw[q * 256 + r * 16 + cf + j] + b_attn[n]);
    }
    *(short8*)(g_energy + (size_t)(rt * 32 + row) * 1024 + nt * 16 + cf) = o;
    __syncthreads();
  }
}

// Prologue: init states, mask output, fused bias b0f, counter.
__global__ void k_init(const float* __restrict__ ehid, const int* __restrict__ lens,
                       const float* __restrict__ Wih0, const float* __restrict__ bp,
                       const float* __restrict__ bih0,
                       float* __restrict__ out, int out_size) {
  int i = blockIdx.x * 256 + threadIdx.x;
  if (i < 16) g_cnt[i] = 0u;
  if (i < 32768) { float v = ehid[i]; g_h0f[i] = v; g_h0b[i] = f2b(v); }
  else if (i < 65536) {
    int j = i - 32768; float v = ehid[32768 + j];
    g_h1f[j] = v; g_h1b[j] = f2b(v);
  } else if (i < 78336) {
    int mi = i - 65536; int b = mi / 400, tt = mi % 400;
    int idx = 1651200 + mi;
    if (idx < out_size) out[idx] = (tt > lens[b]) ? 1.0f : 0.0f;
  } else if (i < 81408) {
    int n = i - 78336;
    float s = bih0[n];
    const float* wr = Wih0 + (size_t)n * 128;
    for (int m = 0; m < 128; ++m) s += bp[m] * wr[m];
    g_b0f[n] = s;
  }
}

// Prologue: gh0/gh1 for step 0 (h_init @ W_hh^T + b_hh).
__global__ void k_pre(const float* __restrict__ b_hh0, const float* __restrict__ b_hh1) {
  const int wg = blockIdx.x, tid = threadIdx.x;
  const int lane = tid & 63, wv = tid >> 6;
  __shared__ __align__(16) float sh[1536];
  const int qa = (wv < 2) ? wv * 2 : wv + 2;
  const int qb = (wv < 2) ? wv * 2 + 1 : -1;
  const ushort_t* Ab = (wg < 64) ? g_h0b : g_h1b;
  const ushort_t* Bw = g_sw + ((wg < 64) ? SB_HH0 : SB_HH1);
  const float* bhh = (wg < 64) ? b_hh0 : b_hh1;
  float* ghb = (wg < 64) ? g_gh0 : g_gh1;
  const int w16 = wg & 63;
  { int g = qa >> 1, mu = qa & 1;
    put_tile(sh, qa, lane, gemm_plain(Ab, Bw, g * 64 + w16, mu, lane)); }
  if (qb >= 0) { int g = qb >> 1, mu = qb & 1;
    put_tile(sh, qb, lane, gemm_plain(Ab, Bw, g * 64 + w16, mu, lane)); }
  __syncthreads();
  const int jl = tid & 15, mr = tid >> 4, jg = w16 * 16 + jl;
#pragma unroll
  for (int mu = 0; mu < 2; ++mu) {
    const int b = mu * 16 + mr;
#pragma unroll
    for (int g = 0; g < 3; ++g)
      ghb[b * 3072 + g * 1024 + jg] = sh[(g * 2 + mu) * 256 + tid] + bhh[g * 1024 + jg];
  }
}

// ---------------------------------------------------------------------------
// s1: GRU0 (WGs 0..63); mel MFMA writers t-1 (64..71); gate writer (72);
// zero ctx/den (73..80). Grid 81.
// ---------------------------------------------------------------------------
__global__ void k_s1(int t, const float* __restrict__ b_ih0, const float* __restrict__ bp,
                     const float* __restrict__ Wg, const float* __restrict__ bg,
                     const int* __restrict__ lens,
                     float* __restrict__ out, int out_size) {
  const int wg = blockIdx.x, tid = threadIdx.x;
  const int lane = tid & 63, wv = tid >> 6;
  __shared__ __align__(16) float sh[1536];
  if (wg < 64) {
    if (t >= TM) return;
    const int qa = (wv < 2) ? wv * 2 : wv + 2;
    const int qb = (wv < 2) ? wv * 2 + 1 : -1;
    const ushort_t* SW = g_sw + SB_WF;
    float4v acc;
    { int g = qa >> 1, mu = qa & 1;
      acc = (t > 0) ? gemm_plain(g_cob, SW, g * 64 + wg, mu, lane)
                    : float4v{0.f, 0.f, 0.f, 0.f};
      put_tile(sh, qa, lane, acc); }
    if (qb >= 0) { int g = qb >> 1, mu = qb & 1;
      acc = (t > 0) ? gemm_plain(g_cob, SW, g * 64 + wg, mu, lane)
                    : float4v{0.f, 0.f, 0.f, 0.f};
      put_tile(sh, qb, lane, acc); }
    __syncthreads();
    const int jl = tid & 15, mr = tid >> 4, jg = wg * 16 + jl;
    const float* bs = (t > 0) ? g_b0f : b_ih0;   // t=0: dec_in = 0 -> plain b_ih0
    const float bir = bs[jg], biz = bs[1024 + jg], bin = bs[2048 + jg];
#pragma unroll
    for (int mu = 0; mu < 2; ++mu) {
      const int b = mu * 16 + mr;
      float gr = sh[mu * 256 + tid]       + bir + g_gh0[b * 3072 + jg];
      float gz = sh[(2 + mu) * 256 + tid] + biz + g_gh0[b * 3072 + 1024 + jg];
      float gn = sh[(4 + mu) * 256 + tid] + bin;
      float r = sigm(gr), z = sigm(gz);
      float nn = tanhf(gn + r * g_gh0[b * 3072 + 2048 + jg]);
      float h = (1.f - z) * nn + z * g_h0f[b * 1024 + jg];
      g_h0f[b * 1024 + jg] = h; g_h0b[b * 1024 + jg] = f2b(h);
    }
  } else if (wg < 72) {
    if (t == 0) return;
    const int nt = wg - 64;
    if (wv < 2)
      put_tile(sh, wv, lane, gemm_plain(g_cob, g_sw + SB_WP, nt, wv, lane));
    __syncthreads();
    const int jl = tid & 15, mr = tid >> 4;
    const int m = nt * 16 + jl;
    const float bpv = bp[m];
#pragma unroll
    for (int mu = 0; mu < 2; ++mu) {
      const int b = mu * 16 + mr;
      const bool mk = (t - 1) > lens[b];
      const float v = mk ? 0.f : (sh[mu * 256 + tid] + bpv);
      const int oidx = b * 51200 + (t - 1) * 128 + m;
      if (oidx < out_size) out[oidx] = v;
    }
  } else if (wg == 72) {
    if (t == 0) return;
    const int b = tid >> 3, seg = tid & 7;
    const float* cop = g_cof + b * 1024 + seg * 128;
    const float* wgp = Wg + seg * 128;
    float s = 0.f;
#pragma unroll 8
    for (int k = 0; k < 128; k += 4) {
      float4v cv = *(const float4v*)(cop + k);
      float4v wv4 = *(const float4v*)(wgp + k);
      s += cv[0] * wv4[0] + cv[1] * wv4[1] + cv[2] * wv4[2] + cv[3] * wv4[3];
    }
    for (int o = 1; o < 8; o <<= 1) s += __shfl_xor(s, o, 64);
    if (seg == 0) {
      const bool mk = (t - 1) > lens[b];
      const float g = mk ? 1000.f : (s + bg[0]);
      const int oidx = 1638400 + b * 400 + (t - 1);
      if (oidx < out_size) out[oidx] = g;
    }
  } else {                      // wg 73..80: zero ctx/den for this step
    const int z0 = (wg - 73) * 256 + tid;
#pragma unroll
    for (int r4 = 0; r4 < 16; ++r4) g_ctxn[z0 + r4 * 2048] = 0.f;
    if (wg == 73 && tid < 32) g_sden[tid] = 0.f;
  }
}

// s2: GRU1 (WGs 0..63); gh0' for next step (64..127). Grid 128.
__global__ void k_s2(const float* __restrict__ b_ih1, const float* __restrict__ b_hh0) {
  const int wg = blockIdx.x, tid = threadIdx.x;
  const int lane = tid & 63, wv = tid >> 6;
  __shared__ __align__(16) float sh[1536];
  const int qa = (wv < 2) ? wv * 2 : wv + 2;
  const int qb = (wv < 2) ? wv * 2 + 1 : -1;
  const bool lo = (wg < 64);
  const int w16 = wg & 63;
  const ushort_t* SW = g_sw + (lo ? SB_IH1 : SB_HH0);
  { int g = qa >> 1, mu = qa & 1;
    put_tile(sh, qa, lane, gemm_plain(g_h0b, SW, g * 64 + w16, mu, lane)); }
  if (qb >= 0) { int g = qb >> 1, mu = qb & 1;
    put_tile(sh, qb, lane, gemm_plain(g_h0b, SW, g * 64 + w16, mu, lane)); }
  __syncthreads();
  const int jl = tid & 15, mr = tid >> 4, jg = w16 * 16 + jl;
  if (lo) {
    const float bir = b_ih1[jg], biz = b_ih1[1024 + jg], bin = b_ih1[2048 + jg];
#pragma unroll
    for (int mu = 0; mu < 2; ++mu) {
      const int b = mu * 16 + mr;
      float gr = sh[mu * 256 + tid]       + bir + g_gh1[b * 3072 + jg];
      float gz = sh[(2 + mu) * 256 + tid] + biz + g_gh1[b * 3072 + 1024 + jg];
      float gn = sh[(4 + mu) * 256 + tid] + bin;
      float r = sigm(gr), z = sigm(gz);
      float nn = tanhf(gn + r * g_gh1[b * 3072 + 2048 + jg]);
      float h = (1.f - z) * nn + z * g_h1f[b * 1024 + jg];
      g_h1f[b * 1024 + jg] = h; g_h1b[b * 1024 + jg] = f2b(h);
    }
  } else {
#pragma unroll
    for (int mu = 0; mu < 2; ++mu) {
      const int b = mu * 16 + mr;
#pragma unroll
      for (int g = 0; g < 3; ++g)
        g_gh0[b * 3072 + g * 1024 + jg] = sh[(g * 2 + mu) * 256 + tid] + b_hh0[g * 1024 + jg];
    }
  }
}

// ---------------------------------------------------------------------------
// s34: attention (WGs 0..255, bf16 energy/enc plain, ctx/den atomics, then
// cnt++); co (256..319, spin once on cnt, h1b plain + ctx sc); gh1'
// (320..383, spin-free). Grid 384.
// ---------------------------------------------------------------------------
__global__ void k_s34(int t, const float* __restrict__ bc,
                      const float* __restrict__ b_hh1) {
  __shared__ __align__(16) float sh[4160];
  const int wg = blockIdx.x, tid = threadIdx.x;
  const int lane = tid & 63, wv = tid >> 6;
  if (wg < 256) {
    const int b = wg >> 3, slot = wg & 7;
    const float* hp = g_h1f + b * 1024;
    float u0[8], u1[8];
    {
      float4v a0 = *(const float4v*)(hp + lane * 8);
      float4v a1 = *(const float4v*)(hp + lane * 8 + 4);
      float4v b0 = *(const float4v*)(hp + 512 + lane * 8);
      float4v b1 = *(const float4v*)(hp + 512 + lane * 8 + 4);
#pragma unroll
      for (int j = 0; j < 4; ++j) {
        u0[j] = a0[j]; u0[4 + j] = a1[j];
        u1[j] = b0[j]; u1[4 + j] = b1[j];
      }
    }
    float cx0[8] = {0.f, 0.f, 0.f, 0.f, 0.f, 0.f, 0.f, 0.f};
    float cx1[8] = {0.f, 0.f, 0.f, 0.f, 0.f, 0.f, 0.f, 0.f};
    float sw = 0.f;
    const size_t base = ((size_t)(b * 512 + slot * 64 + wv * 16)) * 1024 + lane * 8;
    for (int it = 0; it < 16; ++it) {
      const size_t off = base + (size_t)it * 1024;
      short8 g0 = *(const short8*)(g_energy + off);
      short8 g1 = *(const short8*)(g_energy + off + 512);
      short8 e0 = *(const short8*)(g_encb + off);
      short8 e1 = *(const short8*)(g_encb + off + 512);
      float ef0[8], ef1[8];
      float s = 0.f;
#pragma unroll
      for (int j = 0; j < 8; ++j) {
        ef0[j] = b2f((ushort_t)e0[j]);
        ef1[j] = b2f((ushort_t)e1[j]);
        s += u0[j] * b2f((ushort_t)g0[j]) + u1[j] * b2f((ushort_t)g1[j]);
      }
      for (int o = 1; o < 64; o <<= 1) s += __shfl_xor(s, o, 64);
      const float sc = fminf(fmaxf(s, -70.f), 70.f);  // identity in legit regime
      const float p = __expf(sc);
      sw += p;
#pragma unroll
      for (int j = 0; j < 8; ++j) { cx0[j] += p * ef0[j]; cx1[j] += p * ef1[j]; }
    }
#pragma unroll
    for (int j = 0; j < 8; ++j) {
      sh[wv * 1024 + lane * 8 + j]       = cx0[j];
      sh[wv * 1024 + 512 + lane * 8 + j] = cx1[j];
    }
    if (lane == 0) sh[4096 + wv] = sw;
    __syncthreads();
    float4v t4 = {0.f, 0.f, 0.f, 0.f};
#pragma unroll
    for (int v = 0; v < 4; ++v) t4 += *(const float4v*)&sh[v * 1024 + tid * 4];
    float* dst = g_ctxn + b * 1024 + tid * 4;
#pragma unroll
    for (int c = 0; c < 4; ++c) unsafeAtomicAdd(dst + c, t4[c]);
    if (tid == 0)
      unsafeAtomicAdd(&g_sden[b], sh[4096] + sh[4097] + sh[4098] + sh[4099]);
    __syncthreads();                               // drains atomics (vmcnt)
    if (tid == 0) bump(&g_cnt[0]);                 // ctx contribution done
  } else if (wg < 320) {
    const int w16 = wg - 256;
    if (tid == 0) spin1(&g_cnt[0], (unsigned)(t + 1) * 256u);
    __syncthreads();
    if (wv < 2)
      put_tile(sh, wv, lane, gemm_co(g_h1b, g_ctxn, g_sden, g_sw + SB_WC, w16, wv, lane));
    __syncthreads();
    const int jl = tid & 15, mr = tid >> 4;
    const float bcv = bc[w16 * 16 + jl];
#pragma unroll
    for (int mu = 0; mu < 2; ++mu) {
      const int b = mu * 16 + mr;
      const float v = tanhf(sh[mu * 256 + tid] + bcv);
      g_cof[b * 1024 + w16 * 16 + jl] = v;
      g_cob[b * 1024 + w16 * 16 + jl] = f2b(v);
    }
  } else {
    const int w16 = wg - 320;
    const int qa = (wv < 2) ? wv * 2 : wv + 2;
    const int qb = (wv < 2) ? wv * 2 + 1 : -1;
    { int g = qa >> 1, mu = qa & 1;
      put_tile(sh, qa, lane, gemm_plain(g_h1b, g_sw + SB_HH1, g * 64 + w16, mu, lane)); }
    if (qb >= 0) { int g = qb >> 1, mu = qb & 1;
      put_tile(sh, qb, lane, gemm_plain(g_h1b, g_sw + SB_HH1, g * 64 + w16, mu, lane)); }
    __syncthreads();
    const int jl = tid & 15, mr = tid >> 4, jg = w16 * 16 + jl;
#pragma unroll
    for (int mu = 0; mu < 2; ++mu) {
      const int b = mu * 16 + mr;
#pragma unroll
      for (int g = 0; g < 3; ++g)
        g_gh1[b * 3072 + g * 1024 + jg] = sh[(g * 2 + mu) * 256 + tid] + b_hh1[g * 1024 + jg];
    }
  }
}

extern "C" void kernel_launch(void* const* d_in, const int* in_sizes, int n_in,
                              void* d_out, int out_size, void* d_ws, size_t ws_size,
                              hipStream_t stream) {
  const float* ehid  = (const float*)d_in[0];
  const float* enc   = (const float*)d_in[1];
  const int*   lens  = (const int*)d_in[3];
  const float* W_attn= (const float*)d_in[4];
  const float* b_attn= (const float*)d_in[5];
  const float* W_ih0 = (const float*)d_in[6];
  const float* W_hh0 = (const float*)d_in[7];
  const float* b_ih0 = (const float*)d_in[8];
  const float* b_hh0 = (const float*)d_in[9];
  const float* W_ih1 = (const float*)d_in[10];
  const float* W_hh1 = (const float*)d_in[11];
  const float* b_ih1 = (const float*)d_in[12];
  const float* b_hh1 = (const float*)d_in[13];
  const float* Wc    = (const float*)d_in[14];
  const float* bc    = (const float*)d_in[15];
  const float* Wp    = (const float*)d_in[16];
  const float* bp    = (const float*)d_in[17];
  const float* Wg    = (const float*)d_in[18];
  const float* bg    = (const float*)d_in[19];
  float* out = (float*)d_out;

  k_wf    <<<1536, 256, 0, stream>>>(W_ih0, Wp);
  k_encb  <<<8192, 256, 0, stream>>>(enc);
  k_swz   <<<7744, 256, 0, stream>>>(W_ih1, W_hh0, W_hh1, W_attn, Wc, Wp);
  k_energy<<<512,  256, 0, stream>>>(b_attn);
  k_init  <<<318,  256, 0, stream>>>(ehid, lens, W_ih0, bp, b_ih0, out, out_size);
  k_pre   <<<128,  256, 0, stream>>>(b_hh0, b_hh1);
  for (int t = 0; t < TM; ++t) {
    k_s1 <<<81,  256, 0, stream>>>(t, b_ih0, bp, Wg, bg, lens, out, out_size);
    k_s2 <<<128, 256, 0, stream>>>(b_ih1, b_hh0);
    k_s34<<<384, 256, 0, stream>>>(t, bc, b_hh1);
  }
  k_s1<<<81, 256, 0, stream>>>(TM, b_ih0, bp, Wg, bg, lens, out, out_size);
}